// Round 1
// baseline (360.526 us; speedup 1.0000x reference)
//
#include <hip/hip_runtime.h>

#define BATCH 32
#define NRr 32
#define NFf 128
#define NHh 64
#define NFHh 64

// ---------------------------------------------------------------------------
// intra: x -> x + nmlp([x, softmax(qk^T) v])   for all 4 tensors in one launch
// grid = 288 blocks: robot [0,32), frontier [32,160), rh [160,224), fh [224,288)
// each block: one (batch, 32-row chunk)
// ---------------------------------------------------------------------------
__global__ __launch_bounds__(256) void intra_kernel(
    const float* __restrict__ robot, const float* __restrict__ frontier,
    const float* __restrict__ rhist, const float* __restrict__ fhist,
    const float* __restrict__ Wq, const float* __restrict__ bq,
    const float* __restrict__ Wk, const float* __restrict__ bk,
    const float* __restrict__ Wv, const float* __restrict__ bv,
    const float* __restrict__ Wn1, const float* __restrict__ bn1,
    const float* __restrict__ Wn2, const float* __restrict__ bn2,
    float* __restrict__ o_robot, float* __restrict__ o_frontier,
    float* __restrict__ o_rh, float* __restrict__ o_fh)
{
    __shared__ float sXc[1024];    // chunk rows of x (32x32)
    __shared__ float sKV[8192];    // K (N*32) then V (N*32); reused as T (32x256)
    __shared__ float sQ[1024];     // chunk q (32x32)
    __shared__ float sS[4096];     // scores chunk (32 x N)
    __shared__ float sAgg[1024];   // chunk agg (32x32)

    const int blk = blockIdx.x, tid = threadIdx.x;
    const float* xin; float* xout; int N, lgN, b, chunk;
    if (blk < 32)       { xin=robot;    xout=o_robot;    N=32;  lgN=5; b=blk;          chunk=0; }
    else if (blk < 160) { xin=frontier; xout=o_frontier; N=128; lgN=7; b=(blk-32)>>2;  chunk=(blk-32)&3; }
    else if (blk < 224) { xin=rhist;    xout=o_rh;       N=64;  lgN=6; b=(blk-160)>>1; chunk=(blk-160)&1; }
    else                { xin=fhist;    xout=o_fh;       N=64;  lgN=6; b=(blk-224)>>1; chunk=(blk-224)&1; }

    const float* xb = xin + (size_t)b * N * 32;
    const int r0 = chunk << 5;

    // load chunk rows of x into LDS
    {
        int idx = tid;
        #pragma unroll
        for (int it = 0; it < 4; ++it, idx += 256)
            sXc[idx] = xb[(r0 << 5) + idx];
    }

    // K, V for all N rows (x read from global; L1/L2 cached)
    float* sK = sKV;
    float* sV = sKV + (N << 5);
    for (int idx = tid; idx < (N << 5); idx += 256) {
        int j = idx >> 5, d = idx & 31;
        const float* xr = xb + (j << 5);
        const float* wk = Wk + (d << 5);
        const float* wv = Wv + (d << 5);
        float aK = bk[d], aV = bv[d];
        #pragma unroll
        for (int e = 0; e < 32; ++e) { float xv = xr[e]; aK += xv * wk[e]; aV += xv * wv[e]; }
        sK[idx] = aK; sV[idx] = aV;
    }
    __syncthreads();

    // Q for chunk rows
    {
        int idx = tid;
        #pragma unroll
        for (int it = 0; it < 4; ++it, idx += 256) {
            int r = idx >> 5, d = idx & 31;
            const float* xr = sXc + (r << 5);
            const float* wq = Wq + (d << 5);
            float a = bq[d];
            #pragma unroll
            for (int e = 0; e < 32; ++e) a += xr[e] * wq[e];
            sQ[idx] = a;
        }
    }
    __syncthreads();

    // scores chunk: [32, N]
    for (int idx = tid; idx < (N << 5); idx += 256) {
        int r = idx >> lgN, j = idx & (N - 1);
        const float* qr = sQ + (r << 5);
        const float* kr = sK + (j << 5);
        float a = 0.f;
        #pragma unroll
        for (int e = 0; e < 32; ++e) a += qr[e] * kr[e];
        sS[idx] = a;
    }
    __syncthreads();

    // softmax per row: 32 rows x 8 lanes
    {
        int r = tid >> 3, l = tid & 7;
        float* row = sS + (r << lgN);
        float m = -1e30f;
        for (int j = l; j < N; j += 8) m = fmaxf(m, row[j]);
        m = fmaxf(m, __shfl_xor(m, 4));
        m = fmaxf(m, __shfl_xor(m, 2));
        m = fmaxf(m, __shfl_xor(m, 1));
        float s = 0.f;
        for (int j = l; j < N; j += 8) { float ev = __expf(row[j] - m); row[j] = ev; s += ev; }
        s += __shfl_xor(s, 4); s += __shfl_xor(s, 2); s += __shfl_xor(s, 1);
        float inv = 1.0f / s;
        for (int j = l; j < N; j += 8) row[j] *= inv;
    }
    __syncthreads();

    // agg = e @ V
    {
        int idx = tid;
        #pragma unroll
        for (int it = 0; it < 4; ++it, idx += 256) {
            int r = idx >> 5, d = idx & 31;
            const float* er = sS + (r << lgN);
            float a = 0.f;
            for (int j = 0; j < N; ++j) a += er[j] * sV[(j << 5) + d];
            sAgg[idx] = a;
        }
    }
    __syncthreads();

    // T = relu([x, agg] @ Wn1^T + bn1), overlaid on sKV (32x256)
    float* sT = sKV;
    for (int idx = tid; idx < 8192; idx += 256) {
        int r = idx >> 8, h = idx & 255;
        const float* w1 = Wn1 + (h << 6);
        const float* xr = sXc + (r << 5);
        const float* ar = sAgg + (r << 5);
        float a = bn1[h];
        #pragma unroll
        for (int e = 0; e < 32; ++e) a += xr[e] * w1[e];
        #pragma unroll
        for (int e = 0; e < 32; ++e) a += ar[e] * w1[32 + e];
        sT[idx] = fmaxf(a, 0.f);
    }
    __syncthreads();

    // out = x + T @ Wn2^T + bn2
    {
        int idx = tid;
        #pragma unroll
        for (int it = 0; it < 4; ++it, idx += 256) {
            int r = idx >> 5, d = idx & 31;
            const float* tr = sT + (r << 8);
            const float* w2 = Wn2 + (d << 8);
            float a = bn2[d];
            for (int h = 0; h < 256; ++h) a += tr[h] * w2[h];
            xout[((size_t)b * N << 5) + ((r0 + r) << 5) + d] = sXc[idx] + a;
        }
    }
}

// ---------------------------------------------------------------------------
// pre_y: per (b,j) of the y-tensor: yk_j, yv_j, w_j[h] = We1[h,32:64] . yk_j
// two stages per launch (A then B); grid = nBlkA (+ B blocks if any)
// ---------------------------------------------------------------------------
__global__ __launch_bounds__(256) void pre_y_kernel(
    const float* __restrict__ yA, int NyA, float* __restrict__ wOutA, float* __restrict__ yvOutA, int nBlkA,
    const float* __restrict__ yB, int NyB, float* __restrict__ wOutB, float* __restrict__ yvOutB,
    const float* __restrict__ Wk, const float* __restrict__ bk,
    const float* __restrict__ Wv, const float* __restrict__ bv,
    const float* __restrict__ We1)
{
    __shared__ float sY[32], sKr[32];
    const int blk = blockIdx.x, tid = threadIdx.x;
    const float* y; int Ny; float* wOut; float* yvOut; int idx;
    if (blk < nBlkA) { y=yA; Ny=NyA; wOut=wOutA; yvOut=yvOutA; idx=blk; }
    else             { y=yB; Ny=NyB; wOut=wOutB; yvOut=yvOutB; idx=blk-nBlkA; }
    const int j = idx % Ny, b = idx / Ny;
    const float* yr = y + ((size_t)(b * Ny + j)) * 32;
    if (tid < 32) sY[tid] = yr[tid];
    __syncthreads();
    if (tid < 64) {
        int d = tid & 31;
        const float* wm = (tid < 32) ? (Wk + d * 32) : (Wv + d * 32);
        float a = (tid < 32) ? bk[d] : bv[d];
        #pragma unroll
        for (int e = 0; e < 32; ++e) a += sY[e] * wm[e];
        if (tid < 32) sKr[d] = a;
        else          yvOut[((size_t)(b * Ny + j)) * 32 + d] = a;
    }
    __syncthreads();
    {
        const float* w1 = We1 + tid * 65 + 32;
        float a = 0.f;
        #pragma unroll
        for (int e = 0; e < 32; ++e) a += sKr[e] * w1[e];
        wOut[((size_t)(b * Ny + j)) * 256 + tid] = a;
    }
}

// ---------------------------------------------------------------------------
// inter_main: per (b,i): u_i in-block, scores over j via factorized emlp,
// softmax, agg, node-MLP, optional e output. Two stages per launch.
// ---------------------------------------------------------------------------
__global__ __launch_bounds__(256) void inter_main_kernel(
    const float* __restrict__ xA, int NxA, const float* __restrict__ wA, const float* __restrict__ yvA,
    int NyA, const float* __restrict__ disA, float* __restrict__ outA, float* __restrict__ eA, int nBlkA,
    const float* __restrict__ xB, int NxB, const float* __restrict__ wB, const float* __restrict__ yvB,
    int NyB, const float* __restrict__ disB, float* __restrict__ outB, float* __restrict__ eB,
    const float* __restrict__ Wq, const float* __restrict__ bq,
    const float* __restrict__ We1, const float* __restrict__ be1,
    const float* __restrict__ We2,
    const float* __restrict__ Wn1, const float* __restrict__ bn1,
    const float* __restrict__ Wn2, const float* __restrict__ bn2)
{
    __shared__ float sXi[32], sQ[32], sU[256], sC[256], sW2[256], sS[128], sAgg[32], sT[256];
    const int blk = blockIdx.x, tid = threadIdx.x;
    const float* x; int Nx; const float* w; const float* yv; int Ny;
    const float* dis; float* outp; float* ep; int idx;
    if (blk < nBlkA) { x=xA; Nx=NxA; w=wA; yv=yvA; Ny=NyA; dis=disA; outp=outA; ep=eA; idx=blk; }
    else             { x=xB; Nx=NxB; w=wB; yv=yvB; Ny=NyB; dis=disB; outp=outB; ep=eB; idx=blk-nBlkA; }
    const int i = idx % Nx, b = idx / Nx;
    const float* xr = x + ((size_t)(b * Nx + i)) * 32;
    if (tid < 32) sXi[tid] = xr[tid];
    __syncthreads();
    if (tid < 32) {
        const float* wq = Wq + tid * 32;
        float a = bq[tid];
        #pragma unroll
        for (int e = 0; e < 32; ++e) a += sXi[e] * wq[e];
        sQ[tid] = a;
    }
    __syncthreads();
    {   // u_i[h] = We1[h,:32].xq + be1[h];  cache c_h, We2[h]
        const float* w1 = We1 + tid * 65;
        float a = be1[tid];
        #pragma unroll
        for (int e = 0; e < 32; ++e) a += sQ[e] * w1[e];
        sU[tid]  = a;
        sC[tid]  = w1[64];
        sW2[tid] = We2[tid];
    }
    __syncthreads();
    {   // scores: 8 j-groups x 32 h-lanes
        int jj = tid >> 5, hh = tid & 31;
        const float* dr = dis + ((size_t)(b * Nx + i)) * Ny;
        for (int j = jj; j < Ny; j += 8) {
            const float* wr = w + ((size_t)(b * Ny + j)) * 256;
            float dv = dr[j];
            float a = 0.f;
            #pragma unroll
            for (int h8 = 0; h8 < 8; ++h8) {
                int h = hh + (h8 << 5);
                float hid = sU[h] + wr[h] + sC[h] * dv;
                a += sW2[h] * fmaxf(hid, 0.f);
            }
            a += __shfl_xor(a, 16); a += __shfl_xor(a, 8);
            a += __shfl_xor(a, 4);  a += __shfl_xor(a, 2); a += __shfl_xor(a, 1);
            if (hh == 0) sS[j] = a;
        }
    }
    __syncthreads();
    if (tid < 64) {  // softmax over Ny by wave 0
        float m = -1e30f;
        for (int j = tid; j < Ny; j += 64) m = fmaxf(m, sS[j]);
        #pragma unroll
        for (int msk = 32; msk; msk >>= 1) m = fmaxf(m, __shfl_xor(m, msk));
        float s = 0.f;
        for (int j = tid; j < Ny; j += 64) { float ev = __expf(sS[j] - m); sS[j] = ev; s += ev; }
        #pragma unroll
        for (int msk = 32; msk; msk >>= 1) s += __shfl_xor(s, msk);
        float inv = 1.0f / s;
        for (int j = tid; j < Ny; j += 64) sS[j] *= inv;
    }
    __syncthreads();
    if (ep) {
        for (int j = tid; j < Ny; j += 256) ep[((size_t)(b * Nx + i)) * Ny + j] = sS[j];
    }
    if (tid < 32) {  // agg_d = sum_j e_j * yv[j][d]
        float a = 0.f;
        for (int j = 0; j < Ny; ++j) a += sS[j] * yv[((size_t)(b * Ny + j)) * 32 + tid];
        sAgg[tid] = a;
    }
    __syncthreads();
    {   // t_h = relu(Wn1[h,:32].x + Wn1[h,32:].agg + bn1[h])
        const float* w1 = Wn1 + tid * 64;
        float a = bn1[tid];
        #pragma unroll
        for (int e = 0; e < 32; ++e) a += sXi[e] * w1[e];
        #pragma unroll
        for (int e = 0; e < 32; ++e) a += sAgg[e] * w1[32 + e];
        sT[tid] = fmaxf(a, 0.f);
    }
    __syncthreads();
    if (tid < 32) {
        const float* w2 = Wn2 + tid * 256;
        float a = bn2[tid];
        for (int h = 0; h < 256; ++h) a += sT[h] * w2[h];
        outp[((size_t)(b * Nx + i)) * 32 + tid] = sXi[tid] + a;
    }
}

// ---------------------------------------------------------------------------
extern "C" void kernel_launch(void* const* d_in, const int* in_sizes, int n_in,
                              void* d_out, int out_size, void* d_ws, size_t ws_size,
                              hipStream_t stream) {
    const float* robot          = (const float*)d_in[0];
    const float* frontier       = (const float*)d_in[1];
    const float* rh             = (const float*)d_in[2];
    const float* fh             = (const float*)d_in[3];
    const float* robot_frontier = (const float*)d_in[4];
    const float* robot_past     = (const float*)d_in[5];
    const float* frontier_past  = (const float*)d_in[6];
    const float* Wq  = (const float*)d_in[7];  const float* bq  = (const float*)d_in[8];
    const float* Wk  = (const float*)d_in[9];  const float* bk  = (const float*)d_in[10];
    const float* Wv  = (const float*)d_in[11]; const float* bv  = (const float*)d_in[12];
    const float* Wn1 = (const float*)d_in[13]; const float* bn1 = (const float*)d_in[14];
    const float* Wn2 = (const float*)d_in[15]; const float* bn2 = (const float*)d_in[16];
    const float* We1 = (const float*)d_in[17]; const float* be1 = (const float*)d_in[18];
    const float* We2 = (const float*)d_in[19];

    float* out = (float*)d_out;
    float* out_robot    = out;            // 32*32*32   = 32768
    float* out_frontier = out + 32768;    // 32*128*32  = 131072
    float* out_rh       = out + 163840;   // 32*64*32   = 65536
    float* out_fh       = out + 229376;   // 32*64*32   = 65536
    float* out_edge     = out + 294912;   // 32*32*128  = 131072

    float* W = (float*)d_ws;
    float* robot1 = W;                 // 32768
    float* robot2 = W + 32768;         // 32768
    float* nf     = W + 65536;         // 131072
    float* w5     = W + 196608;        // 32*64*256  = 524288
    float* yv5    = W + 720896;        // 65536
    float* w6     = W + 786432;        // 524288
    float* yv6    = W + 1310720;       // 65536
    float* w7     = W + 1376256;       // 32*128*256 = 1048576
    float* yv7    = W + 2424832;       // 131072

    // 1. all four intra-attentions
    intra_kernel<<<288, 256, 0, stream>>>(robot, frontier, rh, fh,
        Wq, bq, Wk, bk, Wv, bv, Wn1, bn1, Wn2, bn2,
        robot1, out_frontier, out_rh, out_fh);

    // 2. y-side precompute for inter stage 5 (y=rh1) and stage 6 (y=fh1)
    pre_y_kernel<<<4096, 256, 0, stream>>>(
        out_rh, NHh, w5, yv5, BATCH * NHh,
        out_fh, NFHh, w6, yv6,
        Wk, bk, Wv, bv, We1);

    // 3. inter stage 5 (robot1 x rh1) and stage 6 (frontier1 x fh1)
    inter_main_kernel<<<5120, 256, 0, stream>>>(
        robot1, NRr, w5, yv5, NHh, robot_past, robot2, (float*)nullptr, BATCH * NRr,
        out_frontier, NFf, w6, yv6, NFHh, frontier_past, nf, (float*)nullptr,
        Wq, bq, We1, be1, We2, Wn1, bn1, Wn2, bn2);

    // 4. y-side precompute for inter stage 7 (y = new_frontier)
    pre_y_kernel<<<4096, 256, 0, stream>>>(
        nf, NFf, w7, yv7, BATCH * NFf,
        nf, NFf, w7, yv7,   // B unused (grid == nBlkA)
        Wk, bk, Wv, bv, We1);

    // 5. inter stage 7 (robot2 x new_frontier) -> final robot + edge
    inter_main_kernel<<<1024, 256, 0, stream>>>(
        robot2, NRr, w7, yv7, NFf, robot_frontier, out_robot, out_edge, BATCH * NRr,
        robot2, NRr, w7, yv7, NFf, robot_frontier, out_robot, out_edge,  // B unused
        Wq, bq, We1, be1, We2, Wn1, bn1, Wn2, bn2);
}

// Round 2
// 223.705 us; speedup vs baseline: 1.6116x; 1.6116x over previous
//
#include <hip/hip_runtime.h>

#define BATCH 32
#define NRr 32
#define NFf 128
#define NHh 64
#define NFHh 64
#define TI 4

__device__ __forceinline__ float dot4(float4 a, float4 b) {
    return fmaf(a.x, b.x, fmaf(a.y, b.y, fmaf(a.z, b.z, a.w * b.w)));
}

// ---------------------------------------------------------------------------
// intra: x -> x + nmlp([x, softmax(qk^T) v])   for all 4 tensors in one launch
// grid = 288 blocks: robot [0,32), frontier [32,160), rh [160,224), fh [224,288)
// ---------------------------------------------------------------------------
__global__ __launch_bounds__(256) void intra_kernel(
    const float* __restrict__ robot, const float* __restrict__ frontier,
    const float* __restrict__ rhist, const float* __restrict__ fhist,
    const float* __restrict__ Wq, const float* __restrict__ bq,
    const float* __restrict__ Wk, const float* __restrict__ bk,
    const float* __restrict__ Wv, const float* __restrict__ bv,
    const float* __restrict__ Wn1, const float* __restrict__ bn1,
    const float* __restrict__ Wn2, const float* __restrict__ bn2,
    float* __restrict__ o_robot, float* __restrict__ o_frontier,
    float* __restrict__ o_rh, float* __restrict__ o_fh)
{
    __shared__ __align__(16) float sXc[1024];    // chunk rows of x (32x32)
    __shared__ __align__(16) float sQ[1024];     // chunk q (32x32)
    __shared__ __align__(16) float sAgg[1024];   // chunk agg (32x32)
    __shared__ __align__(16) float sS[4096];     // scores chunk (32 x N)
    __shared__ __align__(16) float sKT[4128];    // K^T [32][129] (pad kills bank conflicts)
    __shared__ __align__(16) float sVT[8192];    // V (N*32), later overlaid by T (32x256)

    const int blk = blockIdx.x, tid = threadIdx.x;
    const float* xin; float* xout; int N, lgN, b, chunk;
    if (blk < 32)       { xin=robot;    xout=o_robot;    N=32;  lgN=5; b=blk;          chunk=0; }
    else if (blk < 160) { xin=frontier; xout=o_frontier; N=128; lgN=7; b=(blk-32)>>2;  chunk=(blk-32)&3; }
    else if (blk < 224) { xin=rhist;    xout=o_rh;       N=64;  lgN=6; b=(blk-160)>>1; chunk=(blk-160)&1; }
    else                { xin=fhist;    xout=o_fh;       N=64;  lgN=6; b=(blk-224)>>1; chunk=(blk-224)&1; }

    const float* xb = xin + (size_t)b * N * 32;
    const int r0 = chunk << 5;
    const int d = tid & 31;

    // load chunk rows of x into LDS
    {
        int idx = tid;
        #pragma unroll
        for (int it = 0; it < 4; ++it, idx += 256)
            sXc[idx] = xb[(r0 << 5) + idx];
    }

    // K^T, V for all N rows; weight rows hoisted to registers
    {
        const float4* wk4 = (const float4*)(Wk + (d << 5));
        const float4* wv4 = (const float4*)(Wv + (d << 5));
        float4 wk[8], wv[8];
        #pragma unroll
        for (int k = 0; k < 8; ++k) { wk[k] = wk4[k]; wv[k] = wv4[k]; }
        const float bkd = bk[d], bvd = bv[d];
        for (int idx = tid; idx < (N << 5); idx += 256) {
            int j = idx >> 5;
            const float4* xr = (const float4*)(xb + (j << 5));
            float aK = bkd, aV = bvd;
            #pragma unroll
            for (int k = 0; k < 8; ++k) {
                float4 xv = xr[k];
                aK += dot4(wk[k], xv);
                aV += dot4(wv[k], xv);
            }
            sKT[d * 129 + j] = aK;
            sVT[(j << 5) + d] = aV;
        }
    }
    __syncthreads();

    // Q for chunk rows (weight row hoisted)
    {
        const float4* wq4 = (const float4*)(Wq + (d << 5));
        float4 wq[8];
        #pragma unroll
        for (int k = 0; k < 8; ++k) wq[k] = wq4[k];
        const float bqd = bq[d];
        int idx = tid;
        #pragma unroll
        for (int it = 0; it < 4; ++it, idx += 256) {
            int r = idx >> 5;
            const float4* xr = (const float4*)(sXc + (r << 5));
            float a = bqd;
            #pragma unroll
            for (int k = 0; k < 8; ++k) a += dot4(wq[k], xr[k]);
            sQ[idx] = a;
        }
    }
    __syncthreads();

    // scores chunk: [32, N]; K^T reads conflict-free, Q reads broadcast
    for (int idx = tid; idx < (N << 5); idx += 256) {
        int r = idx >> lgN, j = idx & (N - 1);
        const float* qr = sQ + (r << 5);
        float a = 0.f;
        #pragma unroll
        for (int e = 0; e < 32; ++e) a = fmaf(qr[e], sKT[e * 129 + j], a);
        sS[idx] = a;
    }
    __syncthreads();

    // softmax per row: 32 rows x 8 lanes
    {
        int r = tid >> 3, l = tid & 7;
        float* row = sS + (r << lgN);
        float m = -1e30f;
        for (int j = l; j < N; j += 8) m = fmaxf(m, row[j]);
        m = fmaxf(m, __shfl_xor(m, 4));
        m = fmaxf(m, __shfl_xor(m, 2));
        m = fmaxf(m, __shfl_xor(m, 1));
        float s = 0.f;
        for (int j = l; j < N; j += 8) { float ev = __expf(row[j] - m); row[j] = ev; s += ev; }
        s += __shfl_xor(s, 4); s += __shfl_xor(s, 2); s += __shfl_xor(s, 1);
        float inv = 1.0f / s;
        for (int j = l; j < N; j += 8) row[j] *= inv;
    }
    __syncthreads();

    // agg = e @ V
    {
        int idx = tid;
        #pragma unroll
        for (int it = 0; it < 4; ++it, idx += 256) {
            int r = idx >> 5;
            const float* er = sS + (r << lgN);
            float a = 0.f;
            for (int j = 0; j < N; ++j) a = fmaf(er[j], sVT[(j << 5) + d], a);
            sAgg[idx] = a;
        }
    }
    __syncthreads();

    // T = relu([x, agg] @ Wn1^T + bn1): thread h = tid, loop over 32 rows
    float* sT = sVT;
    {
        const float4* w14 = (const float4*)(Wn1 + (tid << 6));
        float4 w1r[16];
        #pragma unroll
        for (int k = 0; k < 16; ++k) w1r[k] = w14[k];
        const float b1 = bn1[tid];
        for (int r = 0; r < 32; ++r) {
            const float4* xr = (const float4*)(sXc + (r << 5));
            const float4* ar = (const float4*)(sAgg + (r << 5));
            float a = b1;
            #pragma unroll
            for (int k = 0; k < 8; ++k) a += dot4(w1r[k], xr[k]);
            #pragma unroll
            for (int k = 0; k < 8; ++k) a += dot4(w1r[8 + k], ar[k]);
            sT[(r << 8) + tid] = fmaxf(a, 0.f);
        }
    }
    __syncthreads();

    // out = x + T @ Wn2^T + bn2: thread (rg=tid>>5, d), 4 rows each, h chunked
    {
        const int rg = tid >> 5;
        float acc[4] = {0.f, 0.f, 0.f, 0.f};
        #pragma unroll
        for (int hc = 0; hc < 4; ++hc) {
            const float4* w24 = (const float4*)(Wn2 + (d << 8) + (hc << 6));
            float4 w2r[16];
            #pragma unroll
            for (int k = 0; k < 16; ++k) w2r[k] = w24[k];
            #pragma unroll
            for (int p = 0; p < 4; ++p) {
                int r = rg + (p << 3);
                const float4* tr = (const float4*)(sT + (r << 8) + (hc << 6));
                float a = 0.f;
                #pragma unroll
                for (int k = 0; k < 16; ++k) a += dot4(w2r[k], tr[k]);
                acc[p] += a;
            }
        }
        const float b2 = bn2[d];
        #pragma unroll
        for (int p = 0; p < 4; ++p) {
            int r = rg + (p << 3);
            xout[((size_t)b * N << 5) + ((r0 + r) << 5) + d] = sXc[(r << 5) + d] + b2 + acc[p];
        }
    }
}

// ---------------------------------------------------------------------------
// pre_y v2: block = 8 j's of the y-tensor: yk, yv, w_j[h] = We1[h,32:64].yk_j
// ---------------------------------------------------------------------------
__global__ __launch_bounds__(256) void pre_y_kernel(
    const float* __restrict__ yA, int NyA, float* __restrict__ wOutA, float* __restrict__ yvOutA, int nBlkA,
    const float* __restrict__ yB, int NyB, float* __restrict__ wOutB, float* __restrict__ yvOutB,
    const float* __restrict__ Wk, const float* __restrict__ bk,
    const float* __restrict__ Wv, const float* __restrict__ bv,
    const float* __restrict__ We1)
{
    __shared__ __align__(16) float sY[256], sK[256];
    const int blk = blockIdx.x, tid = threadIdx.x;
    const float* y; int Ny; float* wOut; float* yvOut; int idx;
    if (blk < nBlkA) { y=yA; Ny=NyA; wOut=wOutA; yvOut=yvOutA; idx=blk; }
    else             { y=yB; Ny=NyB; wOut=wOutB; yvOut=yvOutB; idx=blk-nBlkA; }
    const int chunks = Ny >> 3;
    const int b = idx / chunks, j0 = (idx - b * chunks) << 3;

    // load 8 y rows (256 floats, contiguous)
    sY[tid] = y[((size_t)(b * Ny + j0)) * 32 + tid];
    __syncthreads();

    // yk -> LDS, yv -> global
    {
        int jl = tid >> 5, dd = tid & 31;
        const float4* wk4 = (const float4*)(Wk + (dd << 5));
        const float4* wv4 = (const float4*)(Wv + (dd << 5));
        const float4* yr = (const float4*)(sY + (jl << 5));
        float aK = bk[dd], aV = bv[dd];
        #pragma unroll
        for (int k = 0; k < 8; ++k) {
            float4 yv4 = yr[k];
            aK += dot4(wk4[k], yv4);
            aV += dot4(wv4[k], yv4);
        }
        sK[(jl << 5) + dd] = aK;
        yvOut[((size_t)(b * Ny + j0 + jl)) * 32 + dd] = aV;
    }
    __syncthreads();

    // w rows: thread h = tid computes 8 j's
    {
        const float* w1 = We1 + tid * 65 + 32;
        float acc[8] = {0,0,0,0,0,0,0,0};
        #pragma unroll
        for (int e = 0; e < 32; ++e) {
            float we = w1[e];
            #pragma unroll
            for (int jl = 0; jl < 8; ++jl)
                acc[jl] = fmaf(we, sK[(jl << 5) + e], acc[jl]);
        }
        #pragma unroll
        for (int jl = 0; jl < 8; ++jl)
            wOut[((size_t)(b * Ny + j0 + jl)) * 256 + tid] = acc[jl];
    }
}

// ---------------------------------------------------------------------------
// inter v2: block = (b, tile of TI=4 i's). All phases use 256 threads.
// ---------------------------------------------------------------------------
__global__ __launch_bounds__(256) void inter_main_kernel(
    const float* __restrict__ xA, int NxA, const float* __restrict__ wA, const float* __restrict__ yvA,
    int NyA, const float* __restrict__ disA, float* __restrict__ outA, float* __restrict__ eA, int nBlkA,
    const float* __restrict__ xB, int NxB, const float* __restrict__ wB, const float* __restrict__ yvB,
    int NyB, const float* __restrict__ disB, float* __restrict__ outB, float* __restrict__ eB,
    const float* __restrict__ Wq, const float* __restrict__ bq,
    const float* __restrict__ We1, const float* __restrict__ be1,
    const float* __restrict__ We2,
    const float* __restrict__ Wn1, const float* __restrict__ bn1,
    const float* __restrict__ Wn2, const float* __restrict__ bn2)
{
    __shared__ __align__(16) float sX[128], sQ[128], sAgg[128];
    __shared__ __align__(16) float sDis[512];     // [TI][128]
    __shared__ __align__(16) float sU[1024];      // [TI][256]
    __shared__ __align__(16) float sC[256], sW2[256];
    __shared__ __align__(16) float sS[512];       // [TI][128]
    __shared__ __align__(16) float sRed[1024];    // [8][128] reduction scratch
    __shared__ __align__(16) float sT[1024];      // [TI][256]

    const int blk = blockIdx.x, tid = threadIdx.x;
    const float* x; int Nx; const float* w; const float* yv; int Ny;
    const float* dis; float* outp; float* ep; int idx;
    if (blk < nBlkA) { x=xA; Nx=NxA; w=wA; yv=yvA; Ny=NyA; dis=disA; outp=outA; ep=eA; idx=blk; }
    else             { x=xB; Nx=NxB; w=wB; yv=yvB; Ny=NyB; dis=disB; outp=outB; ep=eB; idx=blk-nBlkA; }
    const int lgNy = (Ny == 128) ? 7 : 6;
    const int tiles = Nx >> 2;                 // Nx / TI
    const int b = idx / tiles, i0 = (idx - b * tiles) << 2;
    const float* xrow = x + ((size_t)(b * Nx + i0)) * 32;

    // phase 0: stage x tile + dis tile
    if (tid < 128) sX[tid] = xrow[tid];
    for (int k = tid; k < (TI << lgNy); k += 256) {
        int il = k >> lgNy, j = k & (Ny - 1);
        sDis[(il << 7) + j] = dis[((size_t)(b * Nx + i0 + il)) * Ny + j];
    }
    __syncthreads();

    // phase 1: Q for 4 rows
    if (tid < 128) {
        int il = tid >> 5, dd = tid & 31;
        const float4* wq4 = (const float4*)(Wq + (dd << 5));
        const float4* xr = (const float4*)(sX + (il << 5));
        float a = bq[dd];
        #pragma unroll
        for (int k = 0; k < 8; ++k) a += dot4(wq4[k], xr[k]);
        sQ[tid] = a;
    }
    __syncthreads();

    // phase 2: u_i[h], c_h, We2[h]
    {
        const float* w1 = We1 + tid * 65;
        float acc[TI];
        const float b1 = be1[tid];
        #pragma unroll
        for (int il = 0; il < TI; ++il) acc[il] = b1;
        #pragma unroll
        for (int e = 0; e < 32; ++e) {
            float we = w1[e];
            #pragma unroll
            for (int il = 0; il < TI; ++il)
                acc[il] = fmaf(we, sQ[(il << 5) + e], acc[il]);
        }
        #pragma unroll
        for (int il = 0; il < TI; ++il) sU[(il << 8) + tid] = acc[il];
        sC[tid] = w1[64];
        sW2[tid] = We2[tid];
    }
    __syncthreads();

    // phase 3: scores via factorized edge-MLP; thread (jg, hh)
    {
        const int jg = tid >> 5, hh = tid & 31;
        for (int j = jg; j < Ny; j += 8) {
            const float* wr = w + ((size_t)(b * Ny + j)) * 256;
            float dv[TI];
            #pragma unroll
            for (int il = 0; il < TI; ++il) dv[il] = sDis[(il << 7) + j];
            float acc[TI] = {0.f, 0.f, 0.f, 0.f};
            #pragma unroll
            for (int h8 = 0; h8 < 8; ++h8) {
                int h = hh + (h8 << 5);
                float wv_ = wr[h];
                float c = sC[h], w2v = sW2[h];
                #pragma unroll
                for (int il = 0; il < TI; ++il) {
                    float hid = fmaf(c, dv[il], sU[(il << 8) + h] + wv_);
                    acc[il] = fmaf(w2v, fmaxf(hid, 0.f), acc[il]);
                }
            }
            #pragma unroll
            for (int m = 16; m; m >>= 1) {
                #pragma unroll
                for (int il = 0; il < TI; ++il) acc[il] += __shfl_xor(acc[il], m);
            }
            if (hh == 0) {
                #pragma unroll
                for (int il = 0; il < TI; ++il) sS[(il << 7) + j] = acc[il];
            }
        }
    }
    __syncthreads();

    // phase 4: softmax — one wave per i-row
    {
        const int il = tid >> 6, lane = tid & 63;
        float m = -1e30f;
        for (int j = lane; j < Ny; j += 64) m = fmaxf(m, sS[(il << 7) + j]);
        #pragma unroll
        for (int msk = 32; msk; msk >>= 1) m = fmaxf(m, __shfl_xor(m, msk));
        float s = 0.f;
        for (int j = lane; j < Ny; j += 64) {
            float ev = __expf(sS[(il << 7) + j] - m);
            sS[(il << 7) + j] = ev; s += ev;
        }
        #pragma unroll
        for (int msk = 32; msk; msk >>= 1) s += __shfl_xor(s, msk);
        float inv = 1.0f / s;
        for (int j = lane; j < Ny; j += 64) sS[(il << 7) + j] *= inv;
    }
    __syncthreads();

    // edge output (stage 7 only)
    if (ep) {
        for (int k = tid; k < (TI << lgNy); k += 256) {
            int il = k >> lgNy, j = k & (Ny - 1);
            ep[((size_t)(b * Nx + i0 + il)) * Ny + j] = sS[(il << 7) + j];
        }
    }

    // phase 5: agg = e @ yv ; thread (jg, d), LDS-tree reduce
    {
        const int jg = tid >> 5, dd = tid & 31;
        float p[TI] = {0.f, 0.f, 0.f, 0.f};
        for (int j = jg; j < Ny; j += 8) {
            float v = yv[((size_t)(b * Ny + j)) * 32 + dd];
            #pragma unroll
            for (int il = 0; il < TI; ++il)
                p[il] = fmaf(sS[(il << 7) + j], v, p[il]);
        }
        #pragma unroll
        for (int il = 0; il < TI; ++il) sRed[(jg << 7) + (il << 5) + dd] = p[il];
    }
    __syncthreads();
    if (tid < 128) {
        float a = 0.f;
        #pragma unroll
        for (int jg = 0; jg < 8; ++jg) a += sRed[(jg << 7) + tid];
        sAgg[tid] = a;
    }
    __syncthreads();

    // phase 7: node-MLP hidden; thread h = tid for 4 rows
    {
        const float4* w14 = (const float4*)(Wn1 + (tid << 6));
        float acc[TI];
        const float b1 = bn1[tid];
        #pragma unroll
        for (int il = 0; il < TI; ++il) acc[il] = b1;
        #pragma unroll
        for (int k = 0; k < 8; ++k) {
            float4 wa = w14[k];
            #pragma unroll
            for (int il = 0; il < TI; ++il)
                acc[il] += dot4(wa, ((const float4*)(sX + (il << 5)))[k]);
        }
        #pragma unroll
        for (int k = 0; k < 8; ++k) {
            float4 wb = w14[8 + k];
            #pragma unroll
            for (int il = 0; il < TI; ++il)
                acc[il] += dot4(wb, ((const float4*)(sAgg + (il << 5)))[k]);
        }
        #pragma unroll
        for (int il = 0; il < TI; ++il) sT[(il << 8) + tid] = fmaxf(acc[il], 0.f);
    }
    __syncthreads();

    // phase 8: out = x + T @ Wn2^T + bn2 ; thread (hg, d), LDS-tree reduce
    {
        const int hg = tid >> 5, dd = tid & 31;
        const float4* w24 = (const float4*)(Wn2 + (dd << 8) + (hg << 5));
        float p[TI] = {0.f, 0.f, 0.f, 0.f};
        #pragma unroll
        for (int k = 0; k < 8; ++k) {
            float4 wv_ = w24[k];
            #pragma unroll
            for (int il = 0; il < TI; ++il)
                p[il] += dot4(wv_, ((const float4*)(sT + (il << 8) + (hg << 5)))[k]);
        }
        #pragma unroll
        for (int il = 0; il < TI; ++il) sRed[(hg << 7) + (il << 5) + dd] = p[il];
    }
    __syncthreads();
    if (tid < 128) {
        int il = tid >> 5, dd = tid & 31;
        float a = bn2[dd] + sX[tid];
        #pragma unroll
        for (int hg = 0; hg < 8; ++hg) a += sRed[(hg << 7) + tid];
        outp[((size_t)(b * Nx + i0 + il)) * 32 + dd] = a;
    }
}

// ---------------------------------------------------------------------------
extern "C" void kernel_launch(void* const* d_in, const int* in_sizes, int n_in,
                              void* d_out, int out_size, void* d_ws, size_t ws_size,
                              hipStream_t stream) {
    const float* robot          = (const float*)d_in[0];
    const float* frontier       = (const float*)d_in[1];
    const float* rh             = (const float*)d_in[2];
    const float* fh             = (const float*)d_in[3];
    const float* robot_frontier = (const float*)d_in[4];
    const float* robot_past     = (const float*)d_in[5];
    const float* frontier_past  = (const float*)d_in[6];
    const float* Wq  = (const float*)d_in[7];  const float* bq  = (const float*)d_in[8];
    const float* Wk  = (const float*)d_in[9];  const float* bk  = (const float*)d_in[10];
    const float* Wv  = (const float*)d_in[11]; const float* bv  = (const float*)d_in[12];
    const float* Wn1 = (const float*)d_in[13]; const float* bn1 = (const float*)d_in[14];
    const float* Wn2 = (const float*)d_in[15]; const float* bn2 = (const float*)d_in[16];
    const float* We1 = (const float*)d_in[17]; const float* be1 = (const float*)d_in[18];
    const float* We2 = (const float*)d_in[19];

    float* out = (float*)d_out;
    float* out_robot    = out;            // 32*32*32   = 32768
    float* out_frontier = out + 32768;    // 32*128*32  = 131072
    float* out_rh       = out + 163840;   // 32*64*32   = 65536
    float* out_fh       = out + 229376;   // 32*64*32   = 65536
    float* out_edge     = out + 294912;   // 32*32*128  = 131072

    float* W = (float*)d_ws;
    float* robot1 = W;                 // 32768
    float* robot2 = W + 32768;         // 32768
    float* nf     = W + 65536;         // 131072
    float* w5     = W + 196608;        // 32*64*256  = 524288
    float* yv5    = W + 720896;        // 65536
    float* w6     = W + 786432;        // 524288
    float* yv6    = W + 1310720;       // 65536
    float* w7     = W + 1376256;       // 32*128*256 = 1048576
    float* yv7    = W + 2424832;       // 131072

    // 1. all four intra-attentions
    intra_kernel<<<288, 256, 0, stream>>>(robot, frontier, rh, fh,
        Wq, bq, Wk, bk, Wv, bv, Wn1, bn1, Wn2, bn2,
        robot1, out_frontier, out_rh, out_fh);

    // 2. y-side precompute for inter stage 5 (y=rh1) and stage 6 (y=fh1)
    pre_y_kernel<<<512, 256, 0, stream>>>(
        out_rh, NHh, w5, yv5, BATCH * NHh / 8,
        out_fh, NFHh, w6, yv6,
        Wk, bk, Wv, bv, We1);

    // 3. inter stage 5 (robot1 x rh1) and stage 6 (frontier1 x fh1)
    inter_main_kernel<<<1280, 256, 0, stream>>>(
        robot1, NRr, w5, yv5, NHh, robot_past, robot2, (float*)nullptr, BATCH * (NRr / TI),
        out_frontier, NFf, w6, yv6, NFHh, frontier_past, nf, (float*)nullptr,
        Wq, bq, We1, be1, We2, Wn1, bn1, Wn2, bn2);

    // 4. y-side precompute for inter stage 7 (y = new_frontier)
    pre_y_kernel<<<512, 256, 0, stream>>>(
        nf, NFf, w7, yv7, BATCH * NFf / 8,
        nf, NFf, w7, yv7,   // B unused (grid == nBlkA)
        Wk, bk, Wv, bv, We1);

    // 5. inter stage 7 (robot2 x new_frontier) -> final robot + edge
    inter_main_kernel<<<256, 256, 0, stream>>>(
        robot2, NRr, w7, yv7, NFf, robot_frontier, out_robot, out_edge, BATCH * (NRr / TI),
        robot2, NRr, w7, yv7, NFf, robot_frontier, out_robot, out_edge,  // B unused
        Wq, bq, We1, be1, We2, Wn1, bn1, Wn2, bn2);
}